// Round 3
// baseline (1503.073 us; speedup 1.0000x reference)
//
#include <hip/hip_runtime.h>
#include <cfloat>

#define ITEMS 64
#define HID   256

__global__ __launch_bounds__(256) void rochet_fwd(
    const float* __restrict__ val,   // [B, 64]
    const float* __restrict__ W,     // [256, 64]
    const float* __restrict__ w0,    // [256]
    float* __restrict__ alloc,       // [B, 64]
    float* __restrict__ pay,         // [B]
    int batch)
{
    int s = blockIdx.x * blockDim.x + threadIdx.x;
    if (s >= batch) return;

    // Load this sample's 64 valuations into registers (16 x float4).
    float v[ITEMS];
    const float4* vp = reinterpret_cast<const float4*>(val + (size_t)s * ITEMS);
    #pragma unroll
    for (int k = 0; k < ITEMS / 4; ++k) {
        float4 t = vp[k];
        v[4*k+0] = t.x; v[4*k+1] = t.y; v[4*k+2] = t.z; v[4*k+3] = t.w;
    }

    // Replicate np/BLAS fp32 semantics bit-for-bit:
    //   dot_j  = sequential fma over i=0..63, accumulator starts at 0.0f
    //            (sgemm microkernel: single accumulator per C element,
    //             ascending k, vfmadd -> single rounding per step)
    //   h_j    = dot_j + w0[j]   (numpy broadcast add: ONE separate rounding)
    //   argmax = strict '>' ascending scan (first occurrence)
    // NOTE: do NOT seed the chain with w0 (R0 bug), do NOT refine in fp64
    // (R1 showed the reference itself is fp32).
    float maxh = -FLT_MAX;
    int   idx  = 0;
    for (int j = 0; j < HID; j += 4) {
        float a0 = 0.0f, a1 = 0.0f, a2 = 0.0f, a3 = 0.0f;
        const float* r0 = W + (size_t)(j + 0) * ITEMS;
        const float* r1 = W + (size_t)(j + 1) * ITEMS;
        const float* r2 = W + (size_t)(j + 2) * ITEMS;
        const float* r3 = W + (size_t)(j + 3) * ITEMS;
        #pragma unroll
        for (int i = 0; i < ITEMS; ++i) {
            float vi = v[i];
            a0 = fmaf(r0[i], vi, a0);
            a1 = fmaf(r1[i], vi, a1);
            a2 = fmaf(r2[i], vi, a2);
            a3 = fmaf(r3[i], vi, a3);
        }
        float h0 = a0 + w0[j + 0];   // separate rounded add, like numpy
        float h1 = a1 + w0[j + 1];
        float h2 = a2 + w0[j + 2];
        float h3 = a3 + w0[j + 3];
        if (h0 > maxh) { maxh = h0; idx = j + 0; }
        if (h1 > maxh) { maxh = h1; idx = j + 1; }
        if (h2 > maxh) { maxh = h2; idx = j + 2; }
        if (h3 > maxh) { maxh = h3; idx = j + 3; }
    }

    bool  pos = maxh > 0.0f;
    float p   = 0.0f;

    // Gather clamped W[idx] (64 KB table, L1/L2-hot), mask, store alloc,
    // and recompute sum(alloc * v) for payments (2e-2 threshold: any
    // accumulation order is fine here).
    const float4* wr = reinterpret_cast<const float4*>(W + (size_t)idx * ITEMS);
    float4*       op = reinterpret_cast<float4*>(alloc + (size_t)s * ITEMS);
    #pragma unroll
    for (int k = 0; k < ITEMS / 4; ++k) {
        float4 t = wr[k];
        float4 o;
        o.x = pos ? fminf(fmaxf(t.x, 0.0f), 1.0f) : 0.0f;
        o.y = pos ? fminf(fmaxf(t.y, 0.0f), 1.0f) : 0.0f;
        o.z = pos ? fminf(fmaxf(t.z, 0.0f), 1.0f) : 0.0f;
        o.w = pos ? fminf(fmaxf(t.w, 0.0f), 1.0f) : 0.0f;
        p = fmaf(o.x, v[4*k+0], p);
        p = fmaf(o.y, v[4*k+1], p);
        p = fmaf(o.z, v[4*k+2], p);
        p = fmaf(o.w, v[4*k+3], p);
        op[k] = o;
    }
    p -= fmaxf(maxh, 0.0f);   // utility
    p = fmaxf(p, 0.0f);
    pay[s] = p;
}

extern "C" void kernel_launch(void* const* d_in, const int* in_sizes, int n_in,
                              void* d_out, int out_size, void* d_ws, size_t ws_size,
                              hipStream_t stream) {
    const float* val = (const float*)d_in[0];   // [B,64]
    const float* W   = (const float*)d_in[1];   // [256,64]
    const float* w0  = (const float*)d_in[2];   // [256]
    float* out = (float*)d_out;
    int batch = in_sizes[0] / ITEMS;            // 1,000,000
    float* alloc = out;                         // [B,64]
    float* pay   = out + (size_t)batch * ITEMS; // [B]

    int block = 256;
    int grid  = (batch + block - 1) / block;
    rochet_fwd<<<grid, block, 0, stream>>>(val, W, w0, alloc, pay, batch);
}

// Round 4
// 814.683 us; speedup vs baseline: 1.8450x; 1.8450x over previous
//
#include <hip/hip_runtime.h>
#include <cfloat>

#define ITEMS 64
#define HID   256
#define BLK   512               // 8 waves
#define WROW  68                // 64 + 4 pad floats; 272 B = 17*16 -> float4-aligned

__global__ __launch_bounds__(BLK, 4) void rochet_fwd(
    const float* __restrict__ val,   // [B, 64]
    const float* __restrict__ W,     // [256, 64]
    const float* __restrict__ w0,    // [256]
    float* __restrict__ alloc,       // [B, 64]
    float* __restrict__ pay,         // [B]
    int batch)
{
    __shared__ float ldsW[HID * WROW];     // 69,632 B, row-major padded
    __shared__ int   stage[BLK];           // packed (idx | pos<<8) per thread

    const int tid  = threadIdx.x;
    const int lane = tid & 63;
    const int wave = tid >> 6;
    const int s    = blockIdx.x * BLK + tid;

    // ---- Stage W into LDS (coalesced float4 reads, padded rows) ----
    {
        const float4* Wg = reinterpret_cast<const float4*>(W);
        #pragma unroll
        for (int u = tid; u < HID * (ITEMS / 4); u += BLK) {
            int r = u >> 4, c = u & 15;
            *reinterpret_cast<float4*>(&ldsW[r * WROW + c * 4]) = Wg[u];
        }
    }
    __syncthreads();

    int   idx  = 0;
    bool  pos  = false;
    float v[ITEMS];
    float maxh = -FLT_MAX;

    if (s < batch) {
        // Load this sample's 64 valuations (16 x float4, coalesced).
        const float4* vp = reinterpret_cast<const float4*>(val + (size_t)s * ITEMS);
        #pragma unroll
        for (int k = 0; k < ITEMS / 4; ++k) {
            float4 t = vp[k];
            v[4*k+0] = t.x; v[4*k+1] = t.y; v[4*k+2] = t.z; v[4*k+3] = t.w;
        }

        // np/BLAS-exact fp32: per row, single sequential fma chain over
        // i ascending starting at 0, then ONE separately-rounded +w0 add.
        // W rows come from LDS via same-address broadcast ds_read_b128.
        for (int j = 0; j < HID; j += 4) {
            const float4* r0 = reinterpret_cast<const float4*>(&ldsW[(j+0) * WROW]);
            const float4* r1 = reinterpret_cast<const float4*>(&ldsW[(j+1) * WROW]);
            const float4* r2 = reinterpret_cast<const float4*>(&ldsW[(j+2) * WROW]);
            const float4* r3 = reinterpret_cast<const float4*>(&ldsW[(j+3) * WROW]);
            float a0 = 0.0f, a1 = 0.0f, a2 = 0.0f, a3 = 0.0f;
            #pragma unroll
            for (int k = 0; k < ITEMS / 4; ++k) {
                float4 w0v = r0[k];
                float4 w1v = r1[k];
                float4 w2v = r2[k];
                float4 w3v = r3[k];
                float vx = v[4*k+0], vy = v[4*k+1], vz = v[4*k+2], vw = v[4*k+3];
                a0 = fmaf(w0v.x, vx, a0); a0 = fmaf(w0v.y, vy, a0);
                a0 = fmaf(w0v.z, vz, a0); a0 = fmaf(w0v.w, vw, a0);
                a1 = fmaf(w1v.x, vx, a1); a1 = fmaf(w1v.y, vy, a1);
                a1 = fmaf(w1v.z, vz, a1); a1 = fmaf(w1v.w, vw, a1);
                a2 = fmaf(w2v.x, vx, a2); a2 = fmaf(w2v.y, vy, a2);
                a2 = fmaf(w2v.z, vz, a2); a2 = fmaf(w2v.w, vw, a2);
                a3 = fmaf(w3v.x, vx, a3); a3 = fmaf(w3v.y, vy, a3);
                a3 = fmaf(w3v.z, vz, a3); a3 = fmaf(w3v.w, vw, a3);
            }
            float h0 = a0 + w0[j + 0];
            float h1 = a1 + w0[j + 1];
            float h2 = a2 + w0[j + 2];
            float h3 = a3 + w0[j + 3];
            if (h0 > maxh) { maxh = h0; idx = j + 0; }
            if (h1 > maxh) { maxh = h1; idx = j + 1; }
            if (h2 > maxh) { maxh = h2; idx = j + 2; }
            if (h3 > maxh) { maxh = h3; idx = j + 3; }
        }
        pos = maxh > 0.0f;

        // Payments: p = sum(clamp(W[idx]) * v) - relu(maxh), from LDS copy.
        float p = 0.0f;
        const float4* wr = reinterpret_cast<const float4*>(&ldsW[idx * WROW]);
        #pragma unroll
        for (int k = 0; k < ITEMS / 4; ++k) {
            float4 t = wr[k];
            float ox = fminf(fmaxf(t.x, 0.0f), 1.0f);
            float oy = fminf(fmaxf(t.y, 0.0f), 1.0f);
            float oz = fminf(fmaxf(t.z, 0.0f), 1.0f);
            float ow = fminf(fmaxf(t.w, 0.0f), 1.0f);
            if (!pos) { ox = oy = oz = ow = 0.0f; }
            p = fmaf(ox, v[4*k+0], p);
            p = fmaf(oy, v[4*k+1], p);
            p = fmaf(oz, v[4*k+2], p);
            p = fmaf(ow, v[4*k+3], p);
        }
        p -= fmaxf(maxh, 0.0f);
        pay[s] = fmaxf(p, 0.0f);   // per-lane dword store, consecutive -> coalesced
    }

    // ---- Wave-cooperative, fully-coalesced alloc store ----
    // Stage (idx,pos) for all threads (OOB threads stage idx=0,pos=0).
    stage[tid] = idx | (pos ? 0x100 : 0);
    // Wave-local producer/consumer (same wave's 64 slots) -> no barrier needed;
    // compiler orders via lgkmcnt.
    const int S0 = blockIdx.x * BLK + wave * 64;   // wave's first sample
    float4* allocF4 = reinterpret_cast<float4*>(alloc) + (size_t)S0 * (ITEMS / 4);
    #pragma unroll
    for (int k = 0; k < 16; ++k) {
        int f = k * 64 + lane;        // float4 index within wave's 16 KB tile
        int t = f >> 4;               // sample-within-wave
        int c = f & 15;               // float4-within-row
        if (S0 + t < batch) {
            int   pk  = stage[wave * 64 + t];
            int   ti  = pk & 0xff;
            bool  tp  = (pk & 0x100) != 0;
            float4 wv = *reinterpret_cast<const float4*>(&ldsW[ti * WROW + c * 4]);
            float4 o;
            o.x = tp ? fminf(fmaxf(wv.x, 0.0f), 1.0f) : 0.0f;
            o.y = tp ? fminf(fmaxf(wv.y, 0.0f), 1.0f) : 0.0f;
            o.z = tp ? fminf(fmaxf(wv.z, 0.0f), 1.0f) : 0.0f;
            o.w = tp ? fminf(fmaxf(wv.w, 0.0f), 1.0f) : 0.0f;
            allocF4[f] = o;           // 64 lanes x 16 B contiguous = 1 KB/instr
        }
    }
}

extern "C" void kernel_launch(void* const* d_in, const int* in_sizes, int n_in,
                              void* d_out, int out_size, void* d_ws, size_t ws_size,
                              hipStream_t stream) {
    const float* val = (const float*)d_in[0];   // [B,64]
    const float* W   = (const float*)d_in[1];   // [256,64]
    const float* w0  = (const float*)d_in[2];   // [256]
    float* out = (float*)d_out;
    int batch = in_sizes[0] / ITEMS;            // 1,000,000
    float* alloc = out;                         // [B,64]
    float* pay   = out + (size_t)batch * ITEMS; // [B]

    int grid = (batch + BLK - 1) / BLK;
    rochet_fwd<<<grid, BLK, 0, stream>>>(val, W, w0, alloc, pay, batch);
}